// Round 6
// baseline (7251.279 us; speedup 1.0000x reference)
//
#include <hip/hip_runtime.h>
#include <hip/hip_bf16.h>
#include <float.h>
#include <math.h>

#define B_  64
#define S_  256
#define E_  300
#define H_  512
#define J4_ 128     // H/4
#define T_  10

// ---- workspace layout (f32 element offsets) ----
// x:     [S][B][E] (+pad)          gathered embeddings, k-contiguous per (s,b)
// hp0:   [2 dir][B][H]             hidden state, parity 0 (k-contiguous per b)
// cb:    [2 dir][J4][B][4]         cell state (block-private)
// hp1:   [2 dir][B][H]             hidden state, parity 1
// houts: [S][2 dir][J4][B][4]      masked hidden outputs (0 where masked)
// feats: [B][S][T]
#define X_OFF     0
#define X_SZ      (S_*B_*E_ + 64)
#define HP0_OFF   (X_OFF + X_SZ)
#define HSLAB2    (2*B_*H_)             // 65536 floats
#define CB_OFF    (HP0_OFF + HSLAB2)
#define HP1_OFF   (CB_OFF + HSLAB2)     // cb size = 2*128*64*4 = 65536 too
#define HOUT_OFF  (HP1_OFF + HSLAB2)
#define HOUT_SZ   (S_*2*J4_*B_*4)
#define FEAT_OFF  (HOUT_OFF + HOUT_SZ)

// -------------------- embedding gather: x[s][b][e] = emb[tok[b][s]][e] --------------------
__global__ void k_gather(const int* __restrict__ tok, const float* __restrict__ emb,
                         float* __restrict__ x) {
    const int total = S_ * B_ * (E_ / 4);     // 1,228,800 float4s
    for (int i = blockIdx.x * blockDim.x + threadIdx.x; i < total;
         i += gridDim.x * blockDim.x) {
        int e4   = i % 75;
        int rest = i / 75;
        int b = rest & 63;
        int s = rest >> 6;
        float4 v = *reinterpret_cast<const float4*>(
            emb + (size_t)tok[b * S_ + s] * E_ + e4 * 4);      // emb rows 1200B, 16B-aligned
        *reinterpret_cast<float4*>(x + ((size_t)(s * B_ + b)) * E_ + e4 * 4) = v;
    }
}

// full 64-lane sum over the k32 dimension of lane = k32*2 + b2 (b2 preserved).
__device__ __forceinline__ float redk(float v) {
    // k-rot 1,2,4  ==  lane row_ror 2,4,8 (within 16-lane rows) — VALU (DPP)
    v += __int_as_float(__builtin_amdgcn_update_dpp(0, __float_as_int(v), 0x122, 0xF, 0xF, false));
    v += __int_as_float(__builtin_amdgcn_update_dpp(0, __float_as_int(v), 0x124, 0xF, 0xF, false));
    v += __int_as_float(__builtin_amdgcn_update_dpp(0, __float_as_int(v), 0x128, 0xF, 0xF, false));
    // k-rot 8,16  ==  lane xor 16, 32
    v += __shfl_xor(v, 16);
    v += __shfl_xor(v, 32);
    return v;
}

// -------------------- one LSTM time step (both directions) --------------------
// grid 512 = (d:2) x (jb:128) x (bh:2); block 256 = 4 waves, wave = gate g (4 j-rows).
// lane = k32*2 + b2: K spread across lanes; weights live in VGPRs (104/lane),
// dot reduction via DPP rotate-adds + 2 shfl_xor. LDS only for the 2KB part handoff.
__global__ __launch_bounds__(256, 2) void k_step(
    const float* __restrict__ wih_f, const float* __restrict__ whh_f, const float* __restrict__ b_f,
    const float* __restrict__ wih_b, const float* __restrict__ whh_b, const float* __restrict__ b_b,
    const int* __restrict__ lengths, float* __restrict__ ws, int sIdx) {

    const int bid = blockIdx.x;
    const int d   = bid >> 8;
    const int jb  = (bid >> 1) & 127;
    const int bh  = bid & 1;
    const int tid = threadIdx.x;
    const int g   = tid >> 6;            // wave = gate 0..3
    const int lane = tid & 63;
    const int k32 = lane >> 1;
    const int b2  = lane & 1;
    const int jbase = jb * 4;

    const float* wih  = d ? wih_b : wih_f;
    const float* whh  = d ? whh_b : whh_f;
    const float* bias = d ? b_b  : b_f;

    // ---- weights into registers: 4 j-rows x 26 k-slices per lane ----
    float w[104];
#pragma unroll
    for (int jl = 0; jl < 4; jl++) {
        const float* wh = whh + (size_t)(g * H_ + jbase + jl) * H_ + k32;
        const float* wx = wih + (size_t)(g * H_ + jbase + jl) * E_ + k32;
#pragma unroll
        for (int i = 0; i < 16; i++) w[jl * 26 + i] = wh[i * 32];
#pragma unroll
        for (int i = 0; i < 9; i++)  w[jl * 26 + 16 + i] = wx[i * 32];
        w[jl * 26 + 25] = (k32 < 12) ? wx[9 * 32] : 0.f;    // e = 288+k32 tail mask
    }

    const int s = d ? (S_ - 1 - sIdx) : sIdx;
    const int p = sIdx & 1;
    const float* hread  = ws + (p ? HP1_OFF : HP0_OFF) + (size_t)d * (B_ * H_);
    float*       hwrite = ws + (p ? HP0_OFF : HP1_OFF) + (size_t)d * (B_ * H_);
    const float* xs     = ws + X_OFF + (size_t)s * (B_ * E_);

    __shared__ float part[4][4][32];     // [gate][j][b-local]

    for (int bo = 0; bo < 16; bo++) {
        const int b = bh * 32 + bo * 2 + b2;
        const float* hb = hread + (size_t)b * H_ + k32;
        const float* xb = xs    + (size_t)b * E_ + k32;

        float hx[26];
#pragma unroll
        for (int i = 0; i < 16; i++) hx[i] = hb[i * 32];
#pragma unroll
        for (int i = 0; i < 10; i++) hx[16 + i] = xb[i * 32];   // i=9 tail: w=0 there

        float a0 = 0.f, a1 = 0.f, a2 = 0.f, a3 = 0.f;
#pragma unroll
        for (int i = 0; i < 26; i++) {
            a0 += w[0 * 26 + i] * hx[i];
            a1 += w[1 * 26 + i] * hx[i];
            a2 += w[2 * 26 + i] * hx[i];
            a3 += w[3 * 26 + i] * hx[i];
        }
        a0 = redk(a0);
        a1 = redk(a1);
        a2 = redk(a2);
        a3 = redk(a3);

        if (lane < 2) {                   // lane==b2 holds its own b's dots
            const int bl = bo * 2 + lane;
            part[g][0][bl] = a0;
            part[g][1][bl] = a1;
            part[g][2][bl] = a2;
            part[g][3][bl] = a3;
        }
    }
    __syncthreads();

    // ---- combine: activations + state update (threads 0..127 = (jl:4 x bl:32)) ----
    if (tid < 128) {
        const int jl = tid >> 5;
        const int bl = tid & 31;
        const int b  = bh * 32 + bl;

        float gv[4];
#pragma unroll
        for (int g2 = 0; g2 < 4; g2++)
            gv[g2] = part[g2][jl][bl] + bias[g2 * H_ + jbase + jl];

        const int  len = lengths[b];
        const bool m   = (s < len);

        const float iG = 1.f / (1.f + expf(-gv[0]));
        const float fG = 1.f / (1.f + expf(-gv[1]));
        const float gG = tanhf(gv[2]);
        const float oG = 1.f / (1.f + expf(-gv[3]));

        float* cp = ws + CB_OFF + ((size_t)(d * J4_ + jb) * B_ + b) * 4 + jl;
        const float c_old = *cp;
        const float c_new = fG * c_old + iG * gG;
        const float h_new = oG * tanhf(c_new);
        const float h_old = hread[(size_t)b * H_ + jbase + jl];

        *cp = m ? c_new : c_old;
        hwrite[(size_t)b * H_ + jbase + jl] = m ? h_new : h_old;
        ws[HOUT_OFF + ((size_t)(s * 2 + d) * J4_ + jb) * (B_ * 4) + b * 4 + jl] = m ? h_new : 0.f;
    }
}

// -------------------- output projection: feats[b][s][t] --------------------
// grid 256 (per s); block 640 = 10 waves (t) x 64 lanes (b)
__global__ __launch_bounds__(640) void k_feats(const float* __restrict__ w_out,
                                               const float* __restrict__ b_out,
                                               float* __restrict__ ws) {
    const int s = blockIdx.x;
    const int t = __builtin_amdgcn_readfirstlane((int)threadIdx.x >> 6);  // 0..9
    const int b = threadIdx.x & 63;
    const float4* hp = reinterpret_cast<const float4*>(ws + HOUT_OFF) + (size_t)s * 2 * J4_ * B_;
    const float* wr = w_out + (size_t)t * (2 * H_);
    float acc = b_out[t];
#pragma unroll 4
    for (int q = 0; q < 2 * J4_; q++) {
        float4 h4 = hp[q * B_ + b];
        const float* wq = wr + q * 4;   // column d*H + j4*4 + ju matches q = d*J4 + j4
        acc += wq[0]*h4.x + wq[1]*h4.y + wq[2]*h4.z + wq[3]*h4.w;
    }
    ws[FEAT_OFF + ((size_t)b * S_ + s) * T_ + t] = acc;
}

// -------------------- Viterbi decode (one wave per batch row) --------------------
__global__ __launch_bounds__(64) void k_viterbi(const float* __restrict__ start_t,
                                                const float* __restrict__ end_t,
                                                const float* __restrict__ trans,
                                                const int* __restrict__ lengths,
                                                const float* __restrict__ ws,
                                                int* __restrict__ out) {
    const int b = blockIdx.x;
    const int lane = threadIdx.x;
    const int tt = (lane < T_) ? lane : 0;
    const float* feats = ws + FEAT_OFF;
    __shared__ unsigned char bpl[S_][T_];

    float tr[T_];
#pragma unroll
    for (int i = 0; i < T_; i++) tr[i] = trans[i * T_ + tt];   // column tt

    const int len = lengths[b];
    const float* fb = feats + (size_t)b * S_ * T_;
    float score = start_t[tt] + fb[tt];

    for (int s = 1; s < S_; s++) {
        float em = fb[s * T_ + tt];
        float best = -FLT_MAX;
        int bi = 0;
#pragma unroll
        for (int i = 0; i < T_; i++) {
            float si = __shfl(score, i);
            float c = si + tr[i];
            if (c > best) { best = c; bi = i; }   // strict > : first-max like argmax
        }
        bool m = (s < len);
        score = m ? (best + em) : score;
        if (lane < T_) bpl[s][lane] = (unsigned char)(m ? bi : lane);
    }

    float tot = score + end_t[tt];
    float best = -FLT_MAX;
    int last = 0;
#pragma unroll
    for (int i = 0; i < T_; i++) {
        float v = __shfl(tot, i);
        if (v > best) { best = v; last = i; }
    }
    __syncthreads();
    if (lane == 0) {
        int tag = last;
        out[b * S_ + (S_ - 1)] = ((S_ - 1) < len) ? tag : 0;
        for (int s = S_ - 2; s >= 0; s--) {
            tag = bpl[s + 1][tag];
            out[b * S_ + s] = (s < len) ? tag : 0;
        }
    }
}

// -------------------- launcher --------------------
extern "C" void kernel_launch(void* const* d_in, const int* in_sizes, int n_in,
                              void* d_out, int out_size, void* d_ws, size_t ws_size,
                              hipStream_t stream) {
    const int*   tok   = (const int*)  d_in[0];
    const int*   len   = (const int*)  d_in[1];
    const float* emb   = (const float*)d_in[2];
    const float* wih_f = (const float*)d_in[3];
    const float* whh_f = (const float*)d_in[4];
    const float* b_f   = (const float*)d_in[5];
    const float* wih_b = (const float*)d_in[6];
    const float* whh_b = (const float*)d_in[7];
    const float* b_b   = (const float*)d_in[8];
    const float* w_out = (const float*)d_in[9];
    const float* b_out = (const float*)d_in[10];
    const float* st    = (const float*)d_in[11];
    const float* en    = (const float*)d_in[12];
    const float* tr    = (const float*)d_in[13];

    float* ws = (float*)d_ws;
    int* out = (int*)d_out;

    // zero parity-0 hidden (both dirs) + cell state (contiguous: HP0 | CB)
    hipMemsetAsync(ws + HP0_OFF, 0, (size_t)(2 * HSLAB2) * sizeof(float), stream);

    k_gather<<<1024, 256, 0, stream>>>(tok, emb, ws + X_OFF);

    for (int sIdx = 0; sIdx < S_; sIdx++) {
        k_step<<<512, 256, 0, stream>>>(wih_f, whh_f, b_f, wih_b, whh_b, b_b, len, ws, sIdx);
    }

    k_feats<<<256, 640, 0, stream>>>(w_out, b_out, ws);
    k_viterbi<<<64, 64, 0, stream>>>(st, en, tr, len, ws, out);
}

// Round 7
// 5099.984 us; speedup vs baseline: 1.4218x; 1.4218x over previous
//
#include <hip/hip_runtime.h>
#include <hip/hip_bf16.h>
#include <float.h>
#include <math.h>

#define B_  64
#define S_  256
#define E_  300
#define E4_ 75      // E/4
#define H_  512
#define J4_ 128     // H/4
#define T_  10
#define NC_ 203     // K chunks of float4: 128 (h) + 75 (x)

// ---- workspace layout (f32 element offsets) ----
// x:     [S][E4][B][4]                 gathered embeddings, float4-interleaved, batch-coalesced
// hbuf:  6 slabs of HSLAB:             slab = p0d0,p0d1, c_d0,c_d1, p1d0,p1d1
//        each slab [J4][B][4]          (hidden/cell state, float4-interleaved)
// houts: [S][2 dir][J4][B][4]          masked hidden outputs (0 where masked)
// feats: [B][S][T]
#define X_OFF     0
#define X_SZ      (S_*E4_*B_*4)
#define HSLAB     (J4_*B_*4)            // 32768 floats per slab
#define HBUF_OFF  (X_OFF + X_SZ)
#define HBUF_SZ   (6*HSLAB)
#define HOUT_OFF  (HBUF_OFF + HBUF_SZ)
#define HOUT_SZ   (S_*2*HSLAB)
#define FEAT_OFF  (HOUT_OFF + HOUT_SZ)
#define FEAT_SZ   (B_*S_*T_)

// -------------------- embedding gather: x[s][e4][b][.] = emb[tok[b][s]][e4*4+.] ----------
__global__ void k_gather(const int* __restrict__ tok, const float* __restrict__ emb,
                         float4* __restrict__ xp) {
    const int total = S_ * E4_ * B_;     // 1,228,800 float4s
    for (int i = blockIdx.x * blockDim.x + threadIdx.x; i < total;
         i += gridDim.x * blockDim.x) {
        int b    = i & 63;
        int rest = i >> 6;
        int e4   = rest % E4_;
        int s    = rest / E4_;
        xp[i] = *reinterpret_cast<const float4*>(
            emb + (size_t)tok[b * S_ + s] * E_ + e4 * 4);   // emb rows are 1200B (16B-aligned)
    }
}

// -------------------- one LSTM time step (both directions) --------------------
// grid 256 = (d:2) x (jb:128); block 512 = 8 waves; lane = batch b.
// Wave w owns K-chunks c = w, w+8, ... (round-robin over 203 float4 chunks of [h|x]),
// computing partials for ALL 16 gate-rows -> each h/x float4 read ONCE per block
// (203 KB/step vs R5's 812 KB), each weight float4 broadcast-read once from LDS.
__global__ __launch_bounds__(512) void k_step(
    const float* __restrict__ wih_f, const float* __restrict__ whh_f, const float* __restrict__ b_f,
    const float* __restrict__ wih_b, const float* __restrict__ whh_b, const float* __restrict__ b_b,
    const int* __restrict__ lengths, float* __restrict__ ws, int sIdx) {

    const int d   = blockIdx.x >> 7;
    const int jb  = blockIdx.x & 127;
    const int tid = threadIdx.x;
    const int w   = tid >> 6;          // wave 0..7
    const int b   = tid & 63;

    const float* wih  = d ? wih_b : wih_f;
    const float* whh  = d ? whh_b : whh_f;
    const float* bias = d ? b_b  : b_f;

    __shared__ float4 wlds[16][NC_];     // [row=g*4+jl][chunk] : 51.97 KB
    __shared__ float  part[8][16][64];   // [wave][row][b]      : 32 KB

    // ---- stage weight tile into LDS (coalesced float4 vector loads, no s_load path) ----
    for (int idx = tid; idx < 16 * NC_; idx += 512) {
        int r = idx / NC_;
        int c = idx - r * NC_;
        int g = r >> 2, jl = r & 3;
        float4 v;
        if (c < 128)
            v = *reinterpret_cast<const float4*>(
                whh + ((size_t)g * H_ + jb * 4 + jl) * H_ + c * 4);
        else
            v = *reinterpret_cast<const float4*>(
                wih + ((size_t)g * H_ + jb * 4 + jl) * E_ + (c - 128) * 4);
        wlds[r][c] = v;
    }
    __syncthreads();

    const int s = d ? (S_ - 1 - sIdx) : sIdx;
    const int p = sIdx & 1;
    const float4* hp = reinterpret_cast<const float4*>(ws + HBUF_OFF + (size_t)(p * 4 + d) * HSLAB);
    const float4* xp = reinterpret_cast<const float4*>(ws + X_OFF) + (size_t)s * E4_ * B_;

    float acc[16];
#pragma unroll
    for (int r = 0; r < 16; r++) acc[r] = 0.f;

    // ---- K loop: chunk c -> 1 coalesced global float4 + 16 LDS broadcasts + 64 FMA ----
    float4 hx = hp[w * B_ + b];          // c0 = w < 128 always
    for (int c = w; c < NC_; c += 8) {
        const int cn = c + 8;
        float4 nxt = make_float4(0.f, 0.f, 0.f, 0.f);
        if (cn < NC_)
            nxt = (cn < 128) ? hp[cn * B_ + b] : xp[(cn - 128) * B_ + b];
#pragma unroll
        for (int r = 0; r < 16; r++) {
            float4 q = wlds[r][c];
            acc[r] += q.x * hx.x + q.y * hx.y + q.z * hx.z + q.w * hx.w;
        }
        hx = nxt;
    }

#pragma unroll
    for (int r = 0; r < 16; r++) part[w][r][b] = acc[r];
    __syncthreads();

    // ---- combine: 8-way reduce + activations + state update (threads 0..255) ----
    if (tid < 256) {
        const int jl = tid >> 6;
        const int b2 = tid & 63;

        float gv[4];
#pragma unroll
        for (int g = 0; g < 4; g++) {
            float sum = 0.f;
#pragma unroll
            for (int w2 = 0; w2 < 8; w2++) sum += part[w2][g * 4 + jl][b2];
            gv[g] = sum + bias[g * H_ + jb * 4 + jl];
        }

        const int  len = lengths[b2];
        const bool m   = (s < len);

        const float iG = 1.f / (1.f + expf(-gv[0]));
        const float fG = 1.f / (1.f + expf(-gv[1]));
        const float gG = tanhf(gv[2]);
        const float oG = 1.f / (1.f + expf(-gv[3]));

        const size_t sidx = (size_t)(jb * B_ + b2) * 4 + jl;
        float* cp = ws + HBUF_OFF + (size_t)(2 + d) * HSLAB + sidx;
        const float c_old = *cp;
        const float c_new = fG * c_old + iG * gG;
        const float h_new = oG * tanhf(c_new);
        const float h_old = ws[HBUF_OFF + (size_t)(p * 4 + d) * HSLAB + sidx];

        *cp = m ? c_new : c_old;
        ws[HBUF_OFF + (size_t)((p ^ 1) * 4 + d) * HSLAB + sidx] = m ? h_new : h_old;
        ws[HOUT_OFF + ((size_t)(s * 2 + d) * J4_ + jb) * (B_ * 4) + b2 * 4 + jl] = m ? h_new : 0.f;
    }
}

// -------------------- output projection: feats[b][s][t] --------------------
// grid 256 (per s); block 640 = 10 waves (t) x 64 lanes (b)
__global__ __launch_bounds__(640) void k_feats(const float* __restrict__ w_out,
                                               const float* __restrict__ b_out,
                                               float* __restrict__ ws) {
    const int s = blockIdx.x;
    const int t = __builtin_amdgcn_readfirstlane((int)threadIdx.x >> 6);  // 0..9
    const int b = threadIdx.x & 63;
    const float4* hp = reinterpret_cast<const float4*>(ws + HOUT_OFF) + (size_t)s * 2 * J4_ * B_;
    const float* wr = w_out + (size_t)t * (2 * H_);
    float acc = b_out[t];
#pragma unroll 4
    for (int q = 0; q < 2 * J4_; q++) {
        float4 h4 = hp[q * B_ + b];
        const float* wq = wr + q * 4;   // column d*H + j4*4 + ju matches q = d*J4 + j4
        acc += wq[0]*h4.x + wq[1]*h4.y + wq[2]*h4.z + wq[3]*h4.w;
    }
    ws[FEAT_OFF + ((size_t)b * S_ + s) * T_ + t] = acc;
}

// -------------------- Viterbi decode (one wave per batch row) --------------------
__global__ __launch_bounds__(64) void k_viterbi(const float* __restrict__ start_t,
                                                const float* __restrict__ end_t,
                                                const float* __restrict__ trans,
                                                const int* __restrict__ lengths,
                                                const float* __restrict__ ws,
                                                int* __restrict__ out) {
    const int b = blockIdx.x;
    const int lane = threadIdx.x;
    const int tt = (lane < T_) ? lane : 0;
    const float* feats = ws + FEAT_OFF;
    __shared__ unsigned char bpl[S_][T_];

    float tr[T_];
#pragma unroll
    for (int i = 0; i < T_; i++) tr[i] = trans[i * T_ + tt];   // column tt

    const int len = lengths[b];
    const float* fb = feats + (size_t)b * S_ * T_;
    float score = start_t[tt] + fb[tt];

    for (int s = 1; s < S_; s++) {
        float em = fb[s * T_ + tt];
        float best = -FLT_MAX;
        int bi = 0;
#pragma unroll
        for (int i = 0; i < T_; i++) {
            float si = __shfl(score, i);
            float c = si + tr[i];
            if (c > best) { best = c; bi = i; }   // strict > : first-max like argmax
        }
        bool m = (s < len);
        score = m ? (best + em) : score;
        if (lane < T_) bpl[s][lane] = (unsigned char)(m ? bi : lane);
    }

    float tot = score + end_t[tt];
    float best = -FLT_MAX;
    int last = 0;
#pragma unroll
    for (int i = 0; i < T_; i++) {
        float v = __shfl(tot, i);
        if (v > best) { best = v; last = i; }
    }
    __syncthreads();
    if (lane == 0) {
        int tag = last;
        out[b * S_ + (S_ - 1)] = ((S_ - 1) < len) ? tag : 0;
        for (int s = S_ - 2; s >= 0; s--) {
            tag = bpl[s + 1][tag];
            out[b * S_ + s] = (s < len) ? tag : 0;
        }
    }
}

// -------------------- launcher --------------------
extern "C" void kernel_launch(void* const* d_in, const int* in_sizes, int n_in,
                              void* d_out, int out_size, void* d_ws, size_t ws_size,
                              hipStream_t stream) {
    const int*   tok   = (const int*)  d_in[0];
    const int*   len   = (const int*)  d_in[1];
    const float* emb   = (const float*)d_in[2];
    const float* wih_f = (const float*)d_in[3];
    const float* whh_f = (const float*)d_in[4];
    const float* b_f   = (const float*)d_in[5];
    const float* wih_b = (const float*)d_in[6];
    const float* whh_b = (const float*)d_in[7];
    const float* b_b   = (const float*)d_in[8];
    const float* w_out = (const float*)d_in[9];
    const float* b_out = (const float*)d_in[10];
    const float* st    = (const float*)d_in[11];
    const float* en    = (const float*)d_in[12];
    const float* tr    = (const float*)d_in[13];

    float* ws = (float*)d_ws;
    int* out = (int*)d_out;

    // zero parity-0 hidden slabs + both cell slabs (slabs 0..3); parity-1 written before read
    hipMemsetAsync(ws + HBUF_OFF, 0, (size_t)4 * HSLAB * sizeof(float), stream);

    k_gather<<<1024, 256, 0, stream>>>(tok, emb, reinterpret_cast<float4*>(ws + X_OFF));

    for (int sIdx = 0; sIdx < S_; sIdx++) {
        k_step<<<256, 512, 0, stream>>>(wih_f, whh_f, b_f, wih_b, whh_b, b_b, len, ws, sIdx);
    }

    k_feats<<<256, 640, 0, stream>>>(w_out, b_out, ws);
    k_viterbi<<<64, 64, 0, stream>>>(st, en, tr, len, ws, out);
}

// Round 8
// 3307.491 us; speedup vs baseline: 2.1924x; 1.5419x over previous
//
#include <hip/hip_runtime.h>
#include <float.h>
#include <math.h>

#define B_  64
#define S_  256
#define E_  300
#define H_  512
#define T_  10

typedef __bf16 bf16x8 __attribute__((ext_vector_type(8)));
typedef float  f32x4  __attribute__((ext_vector_type(4)));

// ---- ws byte-offset layout ----
// A   : packed weights  [d2][jb64][m2][ver2][kb26][lane64][8 bf16]   (13.6 MB)
// BX  : packed x        [ver2][s256][kb10][b64][kg4][8 bf16]         (21.0 MB)
// BH  : packed h        [slab4 = p*2+d][ver2][kb16][b64][kg4][8 bf16] (0.5 MB)
// HST : fp32 h carry    [d2][j512][b64]                              (0.25 MB)
// CST : fp32 c carry    [d2][j512][b64]                              (0.25 MB)
// HOUT: fp32 masked h   [s256][d2][j512][b64]                        (134 MB)
// FEAT: [b64][s256][t10] fp32
#define A_BYTES    (2u*64*2*2*26*64*16)
#define BX_BYTES   (2u*256*10*64*4*8*2)
#define BH_BYTES   (4u*2*16*64*4*8*2)
#define HST_BYTES  (2u*512*64*4)
#define CST_BYTES  (2u*512*64*4)
#define HOUT_BYTES (256u*2*512*64*4)
#define A_OFF    0u
#define BX_OFF   (A_OFF + A_BYTES)
#define BH_OFF   (BX_OFF + BX_BYTES)
#define HST_OFF  (BH_OFF + BH_BYTES)
#define CST_OFF  (HST_OFF + HST_BYTES)
#define HOUT_OFF (CST_OFF + CST_BYTES)
#define FEAT_OFF (HOUT_OFF + HOUT_BYTES)

// -------------------- pack weights into MFMA-fragment order (hi/lo split) --------------------
// thread -> (d, jb, m, kb, lane); writes both ver chunks.
__global__ __launch_bounds__(1024) void k_packw(
    const float* __restrict__ wih_f, const float* __restrict__ whh_f,
    const float* __restrict__ wih_b, const float* __restrict__ whh_b,
    char* __restrict__ ws) {
    unsigned t = blockIdx.x * 1024 + threadIdx.x;      // 425,984 total
    unsigned lane = t & 63; t >>= 6;
    unsigned kb = t % 26;  t /= 26;
    unsigned m  = t & 1;   t >>= 1;
    unsigned jb = t & 63;  t >>= 6;
    unsigned d  = t;
    const float* whh = d ? whh_b : whh_f;
    const float* wih = d ? wih_b : wih_f;
    unsigned r16 = lane & 15, kg = lane >> 4;
    unsigned r = m * 16 + r16;
    unsigned g = r >> 3, jl = r & 7;
    unsigned wrow = g * 512 + jb * 8 + jl;
    bf16x8 vh, vl;
#pragma unroll
    for (int i = 0; i < 8; i++) {
        unsigned k = kb * 32 + kg * 8 + i;
        float x;
        if (k < 512) x = whh[(size_t)wrow * 512 + k];
        else { unsigned e = k - 512; x = (e < 300) ? wih[(size_t)wrow * 300 + e] : 0.f; }
        __bf16 h = (__bf16)x;
        vh[i] = h;
        vl[i] = (__bf16)(x - (float)h);
    }
    bf16x8* A = (bf16x8*)(ws + A_OFF);
    size_t c0 = ((((size_t)(d * 64 + jb) * 2 + m) * 2 + 0) * 26 + kb) * 64 + lane;
    size_t c1 = ((((size_t)(d * 64 + jb) * 2 + m) * 2 + 1) * 26 + kb) * 64 + lane;
    A[c0] = vh;
    A[c1] = vl;
}

// -------------------- gather + pack embeddings into B-fragment order (hi/lo) ----------------
__global__ __launch_bounds__(1024) void k_packx(
    const int* __restrict__ tok, const float* __restrict__ emb, char* __restrict__ ws) {
    unsigned t = blockIdx.x * 1024 + threadIdx.x;      // 655,360 total
    unsigned kg = t & 3;  t >>= 2;
    unsigned b  = t & 63; t >>= 6;
    unsigned kb = t % 10; t /= 10;
    unsigned s  = t;
    const float* row = emb + (size_t)tok[b * S_ + s] * E_;
    bf16x8 vh, vl;
#pragma unroll
    for (int i = 0; i < 8; i++) {
        unsigned e = kb * 32 + kg * 8 + i;
        float x = (e < 300) ? row[e] : 0.f;
        __bf16 h = (__bf16)x;
        vh[i] = h;
        vl[i] = (__bf16)(x - (float)h);
    }
    bf16x8* B = (bf16x8*)(ws + BX_OFF);
    size_t c0 = (((size_t)0 * 256 + s) * 10 + kb) * 256 + b * 4 + kg;
    size_t c1 = (((size_t)1 * 256 + s) * 10 + kb) * 256 + b * 4 + kg;
    B[c0] = vh;
    B[c1] = vl;
}

// -------------------- one LSTM time step: MFMA split-bf16 --------------------
// grid 128 = d*64 + jb (32 gate-rows: r = g*8+jl for 8 j's); block 1024 = 16 waves
// wave w = (m:2, n:4, kh:2); 13 ksteps x 4 split-term MFMAs; all frags 16B/lane coalesced.
__global__ __launch_bounds__(1024) void k_step(
    const float* __restrict__ b_f, const float* __restrict__ b_b,
    const int* __restrict__ lengths, char* __restrict__ ws, int sIdx) {

    const int bid = blockIdx.x;
    const int d  = bid >> 6;
    const int jb = bid & 63;
    const int tid = threadIdx.x;
    const int w = tid >> 6, lane = tid & 63;
    const int m = w >> 3, n = (w >> 1) & 3, kh = w & 1;
    const int s = d ? (S_ - 1 - sIdx) : sIdx;
    const int p = sIdx & 1;

    const bf16x8* A  = (const bf16x8*)(ws + A_OFF);
    const bf16x8* BH = (const bf16x8*)(ws + BH_OFF);
    const bf16x8* BX = (const bf16x8*)(ws + BX_OFF);

    const size_t aBase0 = ((((size_t)(d * 64 + jb) * 2 + m) * 2 + 0) * 26) * 64 + lane;
    const size_t aBase1 = ((((size_t)(d * 64 + jb) * 2 + m) * 2 + 1) * 26) * 64 + lane;
    const int bcol = n * 16 + (lane & 15);
    const int koff = lane >> 4;
    const int slab = p * 2 + d;

    f32x4 acc = {0.f, 0.f, 0.f, 0.f};
    for (int kk = 0; kk < 13; kk++) {
        const int kb = kh * 13 + kk;
        bf16x8 ah = A[aBase0 + (size_t)kb * 64];
        bf16x8 al = A[aBase1 + (size_t)kb * 64];
        bf16x8 bh, bl;
        if (kb < 16) {
            bh = BH[(((size_t)(slab * 2 + 0) * 16) + kb) * 256 + bcol * 4 + koff];
            bl = BH[(((size_t)(slab * 2 + 1) * 16) + kb) * 256 + bcol * 4 + koff];
        } else {
            bh = BX[(((size_t)0 * 256 + s) * 10 + (kb - 16)) * 256 + bcol * 4 + koff];
            bl = BX[(((size_t)1 * 256 + s) * 10 + (kb - 16)) * 256 + bcol * 4 + koff];
        }
        acc = __builtin_amdgcn_mfma_f32_16x16x32_bf16(ah, bh, acc, 0, 0, 0);
        acc = __builtin_amdgcn_mfma_f32_16x16x32_bf16(ah, bl, acc, 0, 0, 0);
        acc = __builtin_amdgcn_mfma_f32_16x16x32_bf16(al, bh, acc, 0, 0, 0);
        acc = __builtin_amdgcn_mfma_f32_16x16x32_bf16(al, bl, acc, 0, 0, 0);
    }

    __shared__ float part[16][4][64];
    __shared__ unsigned short hlds[2][8][64];
    part[w][0][lane] = acc[0];
    part[w][1][lane] = acc[1];
    part[w][2][lane] = acc[2];
    part[w][3][lane] = acc[3];
    __syncthreads();

    // combine: (jl:8, b:64) -> 4 gates, activations, masked state update, h split for next step
    if (tid < 512) {
        const int jl = tid >> 6, b = tid & 63;
        const float* bias = d ? b_b : b_f;
        float gv[4];
#pragma unroll
        for (int g = 0; g < 4; g++) {
            int r = g * 8 + jl;
            int m2 = r >> 4, r16 = r & 15;
            int l = ((r16 >> 2) << 4) + (b & 15);   // C frag: row=(l>>4)*4+q, col=l&15
            int q = r16 & 3;
            int wA = m2 * 8 + ((b >> 4) << 1);
            gv[g] = part[wA][q][l] + part[wA + 1][q][l] + bias[g * 512 + jb * 8 + jl];
        }
        const int  len = lengths[b];
        const bool msk = (s < len);
        const float iG = 1.f / (1.f + expf(-gv[0]));
        const float fG = 1.f / (1.f + expf(-gv[1]));
        const float gG = tanhf(gv[2]);
        const float oG = 1.f / (1.f + expf(-gv[3]));

        float* hstate = (float*)(ws + HST_OFF);
        float* cstate = (float*)(ws + CST_OFF);
        const size_t sidx = ((size_t)d * 512 + jb * 8 + jl) * 64 + b;
        const float c_old = cstate[sidx];
        const float h_old = hstate[sidx];
        const float c_new = fG * c_old + iG * gG;
        const float h_new = oG * tanhf(c_new);
        const float h_pub = msk ? h_new : h_old;
        cstate[sidx] = msk ? c_new : c_old;
        hstate[sidx] = h_pub;
        ((float*)(ws + HOUT_OFF))[(((size_t)s * 2 + d) * 512 + jb * 8 + jl) * 64 + b] =
            msk ? h_new : 0.f;

        __bf16 hh = (__bf16)h_pub;
        __bf16 hl = (__bf16)(h_pub - (float)hh);
        hlds[0][jl][b] = __builtin_bit_cast(unsigned short, hh);
        hlds[1][jl][b] = __builtin_bit_cast(unsigned short, hl);
    }
    __syncthreads();

    // repack this block's 8 h-rows (= next step's k-octet kg=jb&3 of kstep jb>>2) coalesced
    if (tid < 128) {
        const int ver = tid >> 6, b = tid & 63;
        unsigned wd[4];
#pragma unroll
        for (int q2 = 0; q2 < 4; q2++) {
            unsigned lo16 = hlds[ver][q2 * 2 + 0][b];
            unsigned hi16 = hlds[ver][q2 * 2 + 1][b];
            wd[q2] = lo16 | (hi16 << 16);
        }
        const int slab2 = (p ^ 1) * 2 + d;
        uint4* BHw = (uint4*)(ws + BH_OFF);
        BHw[(((size_t)(slab2 * 2 + ver) * 16) + (jb >> 2)) * 256 + b * 4 + (jb & 3)] =
            make_uint4(wd[0], wd[1], wd[2], wd[3]);
    }
}

// -------------------- output projection: feats[b][s][t] --------------------
__global__ __launch_bounds__(640) void k_feats(const float* __restrict__ w_out,
                                               const float* __restrict__ b_out,
                                               char* __restrict__ ws) {
    const int s = blockIdx.x;
    const int t = __builtin_amdgcn_readfirstlane((int)threadIdx.x >> 6);  // 0..9
    const int b = threadIdx.x & 63;
    const float* hrow = (const float*)(ws + HOUT_OFF) + (size_t)s * 2 * 512 * 64;  // [f=d*512+j][b]
    const float* wr = w_out + (size_t)t * 1024;
    float acc = b_out[t];
#pragma unroll 8
    for (int f = 0; f < 1024; f++)
        acc += wr[f] * hrow[(size_t)f * 64 + b];
    ((float*)(ws + FEAT_OFF))[((size_t)b * S_ + s) * T_ + t] = acc;
}

// -------------------- Viterbi decode (one wave per batch row) --------------------
__global__ __launch_bounds__(64) void k_viterbi(const float* __restrict__ start_t,
                                                const float* __restrict__ end_t,
                                                const float* __restrict__ trans,
                                                const int* __restrict__ lengths,
                                                const char* __restrict__ ws,
                                                int* __restrict__ out) {
    const int b = blockIdx.x;
    const int lane = threadIdx.x;
    const int tt = (lane < T_) ? lane : 0;
    const float* feats = (const float*)(ws + FEAT_OFF);
    __shared__ unsigned char bpl[S_][T_];

    float tr[T_];
#pragma unroll
    for (int i = 0; i < T_; i++) tr[i] = trans[i * T_ + tt];   // column tt

    const int len = lengths[b];
    const float* fb = feats + (size_t)b * S_ * T_;
    float score = start_t[tt] + fb[tt];

    for (int s = 1; s < S_; s++) {
        float em = fb[s * T_ + tt];
        float best = -FLT_MAX;
        int bi = 0;
#pragma unroll
        for (int i = 0; i < T_; i++) {
            float si = __shfl(score, i);
            float c = si + tr[i];
            if (c > best) { best = c; bi = i; }   // strict > : first-max like argmax
        }
        bool m = (s < len);
        score = m ? (best + em) : score;
        if (lane < T_) bpl[s][lane] = (unsigned char)(m ? bi : lane);
    }

    float tot = score + end_t[tt];
    float best = -FLT_MAX;
    int last = 0;
#pragma unroll
    for (int i = 0; i < T_; i++) {
        float v = __shfl(tot, i);
        if (v > best) { best = v; last = i; }
    }
    __syncthreads();
    if (lane == 0) {
        int tag = last;
        out[b * S_ + (S_ - 1)] = ((S_ - 1) < len) ? tag : 0;
        for (int s = S_ - 2; s >= 0; s--) {
            tag = bpl[s + 1][tag];
            out[b * S_ + s] = (s < len) ? tag : 0;
        }
    }
}

// -------------------- launcher --------------------
extern "C" void kernel_launch(void* const* d_in, const int* in_sizes, int n_in,
                              void* d_out, int out_size, void* d_ws, size_t ws_size,
                              hipStream_t stream) {
    const int*   tok   = (const int*)  d_in[0];
    const int*   len   = (const int*)  d_in[1];
    const float* emb   = (const float*)d_in[2];
    const float* wih_f = (const float*)d_in[3];
    const float* whh_f = (const float*)d_in[4];
    const float* b_f   = (const float*)d_in[5];
    const float* wih_b = (const float*)d_in[6];
    const float* whh_b = (const float*)d_in[7];
    const float* b_b   = (const float*)d_in[8];
    const float* w_out = (const float*)d_in[9];
    const float* b_out = (const float*)d_in[10];
    const float* st    = (const float*)d_in[11];
    const float* en    = (const float*)d_in[12];
    const float* tr    = (const float*)d_in[13];

    char* ws = (char*)d_ws;
    int* out = (int*)d_out;

    // zero BH (h packed, both parities) + fp32 h/c carries — contiguous 1 MB
    hipMemsetAsync(ws + BH_OFF, 0, BH_BYTES + HST_BYTES + CST_BYTES, stream);

    k_packw<<<416, 1024, 0, stream>>>(wih_f, whh_f, wih_b, whh_b, ws);
    k_packx<<<640, 1024, 0, stream>>>(tok, emb, ws);

    for (int sIdx = 0; sIdx < S_; sIdx++) {
        k_step<<<128, 1024, 0, stream>>>(b_f, b_b, len, ws, sIdx);
    }

    k_feats<<<256, 640, 0, stream>>>(w_out, b_out, ws);
    k_viterbi<<<64, 64, 0, stream>>>(st, en, tr, len, ws, out);
}

// Round 9
// 2274.797 us; speedup vs baseline: 3.1877x; 1.4540x over previous
//
#include <hip/hip_runtime.h>
#include <float.h>
#include <math.h>

#define B_  64
#define S_  256
#define E_  300
#define H_  512
#define T_  10

typedef __bf16 bf16x8 __attribute__((ext_vector_type(8)));
typedef float  f32x4  __attribute__((ext_vector_type(4)));

// ---- ws byte-offset layout ----
// A   : packed weights  [d2][jb128][ver2][kb26][lane64][8 bf16]      (13.6 MB)
// BX  : packed x        [ver2][s256][kb10][b64][kg4][8 bf16]         (21.0 MB)
// BH  : packed h        [slab4 = p*2+d][ver2][kb16][b64][kg4][8 bf16] (0.5 MB)
// HST : fp32 h carry    [d2][j512][b64]                              (0.25 MB)
// CST : fp32 c carry    [d2][j512][b64]                              (0.25 MB)
// HOUT: fp32 masked h   [s256][d2][j512][b64]                        (134 MB)
// FEAT: [b64][s256][t10] fp32
#define A_BYTES    (2u*128*2*26*64*16)
#define BX_BYTES   (2u*256*10*64*4*8*2)
#define BH_BYTES   (4u*2*16*64*4*8*2)
#define HST_BYTES  (2u*512*64*4)
#define CST_BYTES  (2u*512*64*4)
#define HOUT_BYTES (256u*2*512*64*4)
#define A_OFF    0u
#define BX_OFF   (A_OFF + A_BYTES)
#define BH_OFF   (BX_OFF + BX_BYTES)
#define HST_OFF  (BH_OFF + BH_BYTES)
#define CST_OFF  (HST_OFF + HST_BYTES)
#define HOUT_OFF (CST_OFF + CST_BYTES)
#define FEAT_OFF (HOUT_OFF + HOUT_BYTES)

// -------------------- pack weights into MFMA-fragment order (hi/lo split) --------------------
// thread -> (d, jb, kb, lane); writes both ver chunks. 425,984 threads = 416 x 1024.
__global__ __launch_bounds__(1024) void k_packw(
    const float* __restrict__ wih_f, const float* __restrict__ whh_f,
    const float* __restrict__ wih_b, const float* __restrict__ whh_b,
    char* __restrict__ ws) {
    unsigned t = blockIdx.x * 1024 + threadIdx.x;
    unsigned lane = t & 63; t >>= 6;
    unsigned kb = t % 26;  t /= 26;
    unsigned jb = t & 127; t >>= 7;
    unsigned d  = t;
    const float* whh = d ? whh_b : whh_f;
    const float* wih = d ? wih_b : wih_f;
    unsigned r16 = lane & 15, kg = lane >> 4;
    unsigned g = r16 >> 2, jl = r16 & 3;
    unsigned wrow = g * 512 + jb * 4 + jl;
    bf16x8 vh, vl;
#pragma unroll
    for (int i = 0; i < 8; i++) {
        unsigned k = kb * 32 + kg * 8 + i;
        float x;
        if (k < 512) x = whh[(size_t)wrow * 512 + k];
        else { unsigned e = k - 512; x = (e < 300) ? wih[(size_t)wrow * 300 + e] : 0.f; }
        __bf16 h = (__bf16)x;
        vh[i] = h;
        vl[i] = (__bf16)(x - (float)h);
    }
    bf16x8* A = (bf16x8*)(ws + A_OFF);
    size_t c0 = (((size_t)(d * 128 + jb) * 2 + 0) * 26 + kb) * 64 + lane;
    size_t c1 = (((size_t)(d * 128 + jb) * 2 + 1) * 26 + kb) * 64 + lane;
    A[c0] = vh;
    A[c1] = vl;
}

// -------------------- gather + pack embeddings into B-fragment order (hi/lo) ----------------
__global__ __launch_bounds__(1024) void k_packx(
    const int* __restrict__ tok, const float* __restrict__ emb, char* __restrict__ ws) {
    unsigned t = blockIdx.x * 1024 + threadIdx.x;      // 655,360 total
    unsigned kg = t & 3;  t >>= 2;
    unsigned b  = t & 63; t >>= 6;
    unsigned kb = t % 10; t /= 10;
    unsigned s  = t;
    const float* row = emb + (size_t)tok[b * S_ + s] * E_;
    bf16x8 vh, vl;
#pragma unroll
    for (int i = 0; i < 8; i++) {
        unsigned e = kb * 32 + kg * 8 + i;
        float x = (e < 300) ? row[e] : 0.f;
        __bf16 h = (__bf16)x;
        vh[i] = h;
        vl[i] = (__bf16)(x - (float)h);
    }
    bf16x8* B = (bf16x8*)(ws + BX_OFF);
    size_t c0 = (((size_t)0 * 256 + s) * 10 + kb) * 256 + b * 4 + kg;
    size_t c1 = (((size_t)1 * 256 + s) * 10 + kb) * 256 + b * 4 + kg;
    B[c0] = vh;
    B[c1] = vl;
}

// -------------------- one LSTM time step: MFMA split-bf16 --------------------
// grid 256 = d*128 + jb (16 gate-rows: r16 = g*4+jl, j = jb*4+jl); block 1024 = 16 waves
// wave w = (n:4, kh:4); kb split 7/7/6/6; 4 split-term MFMAs per kb; frags 16B/lane coalesced.
__global__ __launch_bounds__(1024) void k_step(
    const float* __restrict__ b_f, const float* __restrict__ b_b,
    const int* __restrict__ lengths, char* __restrict__ ws, int sIdx) {

    const int bid = blockIdx.x;
    const int d  = bid >> 7;
    const int jb = bid & 127;
    const int tid = threadIdx.x;
    const int w = tid >> 6, lane = tid & 63;
    const int n = w >> 2, kh = w & 3;
    const int s = d ? (S_ - 1 - sIdx) : sIdx;
    const int p = sIdx & 1;

    const bf16x8* A  = (const bf16x8*)(ws + A_OFF);
    const bf16x8* BH = (const bf16x8*)(ws + BH_OFF);
    const bf16x8* BX = (const bf16x8*)(ws + BX_OFF);

    const size_t aBase0 = ((((size_t)(d * 128 + jb) * 2 + 0) * 26) * 64) + lane;
    const size_t aBase1 = ((((size_t)(d * 128 + jb) * 2 + 1) * 26) * 64) + lane;
    const int bcol = n * 16 + (lane & 15);
    const int koff = lane >> 4;
    const int slab = p * 2 + d;

    const int kbeg = (kh < 2) ? kh * 7 : 14 + (kh - 2) * 6;
    const int kcnt = (kh < 2) ? 7 : 6;

    f32x4 acc = {0.f, 0.f, 0.f, 0.f};
#pragma unroll 4
    for (int kk = 0; kk < kcnt; kk++) {
        const int kb = kbeg + kk;
        bf16x8 ah = A[aBase0 + (size_t)kb * 64];
        bf16x8 al = A[aBase1 + (size_t)kb * 64];
        bf16x8 bh, bl;
        if (kb < 16) {
            bh = BH[(((size_t)(slab * 2 + 0) * 16) + kb) * 256 + bcol * 4 + koff];
            bl = BH[(((size_t)(slab * 2 + 1) * 16) + kb) * 256 + bcol * 4 + koff];
        } else {
            bh = BX[(((size_t)0 * 256 + s) * 10 + (kb - 16)) * 256 + bcol * 4 + koff];
            bl = BX[(((size_t)1 * 256 + s) * 10 + (kb - 16)) * 256 + bcol * 4 + koff];
        }
        acc = __builtin_amdgcn_mfma_f32_16x16x32_bf16(ah, bh, acc, 0, 0, 0);
        acc = __builtin_amdgcn_mfma_f32_16x16x32_bf16(ah, bl, acc, 0, 0, 0);
        acc = __builtin_amdgcn_mfma_f32_16x16x32_bf16(al, bh, acc, 0, 0, 0);
        acc = __builtin_amdgcn_mfma_f32_16x16x32_bf16(al, bl, acc, 0, 0, 0);
    }

    __shared__ float part[16][4][64];
    __shared__ unsigned short hlds[2][4][64];
    part[w][0][lane] = acc[0];
    part[w][1][lane] = acc[1];
    part[w][2][lane] = acc[2];
    part[w][3][lane] = acc[3];
    __syncthreads();

    // combine: (jl:4, b:64) -> 4 gates, activations, masked state update, h split for next step
    if (tid < 256) {
        const int jl = tid >> 6, b = tid & 63;
        const float* bias = d ? b_b : b_f;
        const int wbase = (b >> 4) * 4;           // n-wave group for this b
        float gv[4];
#pragma unroll
        for (int g = 0; g < 4; g++) {
            const int l = g * 16 + (b & 15);      // C frag: row=(l>>4)*4+q -> g*4+jl, col=l&15
            gv[g] = part[wbase + 0][jl][l] + part[wbase + 1][jl][l]
                  + part[wbase + 2][jl][l] + part[wbase + 3][jl][l]
                  + bias[g * 512 + jb * 4 + jl];
        }
        const int  len = lengths[b];
        const bool msk = (s < len);
        const float iG = 1.f / (1.f + expf(-gv[0]));
        const float fG = 1.f / (1.f + expf(-gv[1]));
        const float gG = tanhf(gv[2]);
        const float oG = 1.f / (1.f + expf(-gv[3]));

        float* hstate = (float*)(ws + HST_OFF);
        float* cstate = (float*)(ws + CST_OFF);
        const size_t sidx = ((size_t)d * 512 + jb * 4 + jl) * 64 + b;
        const float c_old = cstate[sidx];
        const float h_old = hstate[sidx];
        const float c_new = fG * c_old + iG * gG;
        const float h_new = oG * tanhf(c_new);
        const float h_pub = msk ? h_new : h_old;
        cstate[sidx] = msk ? c_new : c_old;
        hstate[sidx] = h_pub;
        ((float*)(ws + HOUT_OFF))[(((size_t)s * 2 + d) * 512 + jb * 4 + jl) * 64 + b] =
            msk ? h_new : 0.f;

        __bf16 hh = (__bf16)h_pub;
        __bf16 hl = (__bf16)(h_pub - (float)hh);
        hlds[0][jl][b] = __builtin_bit_cast(unsigned short, hh);
        hlds[1][jl][b] = __builtin_bit_cast(unsigned short, hl);
    }
    __syncthreads();

    // repack this block's 4 h-rows: they form half of one bf16x8 fragment slot
    // j = jb*4+jl -> kb = jb>>3, kg = (jb>>1)&3, i = (jb&1)*4 + jl
    if (tid < 128) {
        const int ver = tid >> 6, b = tid & 63;
        uint2 wd;
        wd.x = (unsigned)hlds[ver][0][b] | ((unsigned)hlds[ver][1][b] << 16);
        wd.y = (unsigned)hlds[ver][2][b] | ((unsigned)hlds[ver][3][b] << 16);
        const int slab2 = (p ^ 1) * 2 + d;
        char* dst = ws + BH_OFF +
            ((((size_t)(slab2 * 2 + ver) * 16) + (jb >> 3)) * 256 + b * 4 + ((jb >> 1) & 3)) * 16
            + (jb & 1) * 8;
        *reinterpret_cast<uint2*>(dst) = wd;
    }
}

// -------------------- output projection: feats[b][s][t] --------------------
__global__ __launch_bounds__(640) void k_feats(const float* __restrict__ w_out,
                                               const float* __restrict__ b_out,
                                               char* __restrict__ ws) {
    const int s = blockIdx.x;
    const int t = __builtin_amdgcn_readfirstlane((int)threadIdx.x >> 6);  // 0..9
    const int b = threadIdx.x & 63;
    const float* hrow = (const float*)(ws + HOUT_OFF) + (size_t)s * 2 * 512 * 64;  // [f=d*512+j][b]
    const float* wr = w_out + (size_t)t * 1024;
    float acc = b_out[t];
#pragma unroll 8
    for (int f = 0; f < 1024; f++)
        acc += wr[f] * hrow[(size_t)f * 64 + b];
    ((float*)(ws + FEAT_OFF))[((size_t)b * S_ + s) * T_ + t] = acc;
}

// -------------------- Viterbi decode (one wave per batch row) --------------------
__global__ __launch_bounds__(64) void k_viterbi(const float* __restrict__ start_t,
                                                const float* __restrict__ end_t,
                                                const float* __restrict__ trans,
                                                const int* __restrict__ lengths,
                                                const char* __restrict__ ws,
                                                int* __restrict__ out) {
    const int b = blockIdx.x;
    const int lane = threadIdx.x;
    const int tt = (lane < T_) ? lane : 0;
    const float* feats = (const float*)(ws + FEAT_OFF);
    __shared__ unsigned char bpl[S_][T_];

    float tr[T_];
#pragma unroll
    for (int i = 0; i < T_; i++) tr[i] = trans[i * T_ + tt];   // column tt

    const int len = lengths[b];
    const float* fb = feats + (size_t)b * S_ * T_;
    float score = start_t[tt] + fb[tt];

    for (int s = 1; s < S_; s++) {
        float em = fb[s * T_ + tt];
        float best = -FLT_MAX;
        int bi = 0;
#pragma unroll
        for (int i = 0; i < T_; i++) {
            float si = __shfl(score, i);
            float c = si + tr[i];
            if (c > best) { best = c; bi = i; }   // strict > : first-max like argmax
        }
        bool m = (s < len);
        score = m ? (best + em) : score;
        if (lane < T_) bpl[s][lane] = (unsigned char)(m ? bi : lane);
    }

    float tot = score + end_t[tt];
    float best = -FLT_MAX;
    int last = 0;
#pragma unroll
    for (int i = 0; i < T_; i++) {
        float v = __shfl(tot, i);
        if (v > best) { best = v; last = i; }
    }
    __syncthreads();
    if (lane == 0) {
        int tag = last;
        out[b * S_ + (S_ - 1)] = ((S_ - 1) < len) ? tag : 0;
        for (int s = S_ - 2; s >= 0; s--) {
            tag = bpl[s + 1][tag];
            out[b * S_ + s] = (s < len) ? tag : 0;
        }
    }
}

// -------------------- launcher --------------------
extern "C" void kernel_launch(void* const* d_in, const int* in_sizes, int n_in,
                              void* d_out, int out_size, void* d_ws, size_t ws_size,
                              hipStream_t stream) {
    const int*   tok   = (const int*)  d_in[0];
    const int*   len   = (const int*)  d_in[1];
    const float* emb   = (const float*)d_in[2];
    const float* wih_f = (const float*)d_in[3];
    const float* whh_f = (const float*)d_in[4];
    const float* b_f   = (const float*)d_in[5];
    const float* wih_b = (const float*)d_in[6];
    const float* whh_b = (const float*)d_in[7];
    const float* b_b   = (const float*)d_in[8];
    const float* w_out = (const float*)d_in[9];
    const float* b_out = (const float*)d_in[10];
    const float* st    = (const float*)d_in[11];
    const float* en    = (const float*)d_in[12];
    const float* tr    = (const float*)d_in[13];

    char* ws = (char*)d_ws;
    int* out = (int*)d_out;

    // zero BH (h packed, both parities) + fp32 h/c carries — contiguous 1 MB
    hipMemsetAsync(ws + BH_OFF, 0, BH_BYTES + HST_BYTES + CST_BYTES, stream);

    k_packw<<<416, 1024, 0, stream>>>(wih_f, whh_f, wih_b, whh_b, ws);
    k_packx<<<640, 1024, 0, stream>>>(tok, emb, ws);

    for (int sIdx = 0; sIdx < S_; sIdx++) {
        k_step<<<256, 1024, 0, stream>>>(b_f, b_b, len, ws, sIdx);
    }

    k_feats<<<256, 640, 0, stream>>>(w_out, b_out, ws);
    k_viterbi<<<64, 64, 0, stream>>>(st, en, tr, len, ws, out);
}